// Round 1
// baseline (193.320 us; speedup 1.0000x reference)
//
#include <hip/hip_runtime.h>
#include <hip/hip_fp16.h>

typedef _Float16 f16x8 __attribute__((ext_vector_type(8)));
typedef _Float16 f16x4 __attribute__((ext_vector_type(4)));
typedef float f32x4 __attribute__((ext_vector_type(4)));

#define D_MODEL 1024
#define SEQ 1024
#define BATCH 4
#define NH 16
#define DV 64
#define M_TOTAL (BATCH * SEQ)   // 4096

__device__ __forceinline__ void gload16(const _Float16* g, _Float16* lds) {
    __builtin_amdgcn_global_load_lds((const __attribute__((address_space(1))) void*)g,
                                     (__attribute__((address_space(3))) void*)lds,
                                     16, 0, 0);
}

// ---------------- fp32 -> fp16 convert (8 elems/thread) ----------------
__global__ void cvt_f32_f16(const float* __restrict__ s, _Float16* __restrict__ d, int n) {
    int i = (blockIdx.x * blockDim.x + threadIdx.x) * 8;
    if (i >= n) return;
    float4 a = *(const float4*)(s + i);
    float4 b = *(const float4*)(s + i + 4);
    f16x8 h;
    h[0] = (_Float16)a.x; h[1] = (_Float16)a.y; h[2] = (_Float16)a.z; h[3] = (_Float16)a.w;
    h[4] = (_Float16)b.x; h[5] = (_Float16)b.y; h[6] = (_Float16)b.z; h[7] = (_Float16)b.w;
    *(f16x8*)(d + i) = h;
}

// ---------------- fused QKV projection GEMM ----------------
// C[m,o] = sum_k X[m,k] * W[o,k] + b[o]   (NT GEMM, both contiguous along K)
// grid.x = M/128 (32), grid.y = 24 (3 matrices x 8 n-tiles)
// Q,K written as [bh][s][dv] fp16 (Q pre-scaled by 0.125); V written transposed [bh][dv][s].
__global__ __launch_bounds__(256) void qkv_gemm(
    const _Float16* __restrict__ X,
    const _Float16* __restrict__ W0, const _Float16* __restrict__ W1, const _Float16* __restrict__ W2,
    const float* __restrict__ b0, const float* __restrict__ b1, const float* __restrict__ b2,
    _Float16* __restrict__ Qo, _Float16* __restrict__ Ko, _Float16* __restrict__ Vto)
{
    __shared__ _Float16 As[128][64];
    __shared__ _Float16 Bs[128][64];

    const int tid = threadIdx.x;
    const int l = tid & 63;
    const int w = tid >> 6;
    const int mt = blockIdx.x;
    const int ntg = blockIdx.y;
    const int mat = ntg >> 3;        // 0=Q 1=K 2=V
    const int nt  = ntg & 7;
    const _Float16* Wm  = (mat == 0) ? W0 : (mat == 1 ? W1 : W2);
    const float*    bia = (mat == 0) ? b0 : (mat == 1 ? b1 : b2);
    const int m0 = mt * 128, n0 = nt * 128;

    // staging: chunk c covers rows c*32 + w*8 + (l>>3), cols (l&7)*8  (8 halves = 16B per lane)
    const int srow = w * 8 + (l >> 3);
    const int scol = (l & 7) * 8;
    const _Float16* xsrc = X  + (size_t)(m0 + srow) * D_MODEL + scol;
    const _Float16* wsrc = Wm + (size_t)(n0 + srow) * D_MODEL + scol;
    _Float16* aldsb = (_Float16*)As + w * 512;
    _Float16* bldsb = (_Float16*)Bs + w * 512;

    f32x4 acc[4][4] = {};
    const int wm = (w >> 1) * 64, wn = (w & 1) * 64;
    const int fr = l & 15, g = l >> 4;

    for (int kt = 0; kt < 16; ++kt) {
        const int k0 = kt * 64;
#pragma unroll
        for (int c = 0; c < 4; ++c) {
            gload16(xsrc + (size_t)(c * 32) * D_MODEL + k0, aldsb + c * 2048);
            gload16(wsrc + (size_t)(c * 32) * D_MODEL + k0, bldsb + c * 2048);
        }
        __syncthreads();
#pragma unroll
        for (int ks = 0; ks < 2; ++ks) {
            f16x8 a[4], b[4];
#pragma unroll
            for (int i = 0; i < 4; ++i) {
                a[i] = *(const f16x8*)&As[wm + i * 16 + fr][ks * 32 + g * 8];
                b[i] = *(const f16x8*)&Bs[wn + i * 16 + fr][ks * 32 + g * 8];
            }
#pragma unroll
            for (int i = 0; i < 4; ++i)
#pragma unroll
                for (int j = 0; j < 4; ++j)
                    acc[i][j] = __builtin_amdgcn_mfma_f32_16x16x32_f16(a[i], b[j], acc[i][j], 0, 0, 0);
        }
        __syncthreads();
    }

    // epilogue: bias + (Q only) 0.125 scale, scatter to per-head layouts
    const float scale = (mat == 0) ? 0.125f : 1.0f;
#pragma unroll
    for (int j = 0; j < 4; ++j) {
        const int o = n0 + wn + j * 16 + fr;
        const float bb = bia[o];
        const int h = o >> 6, dd = o & 63;
#pragma unroll
        for (int i = 0; i < 4; ++i) {
#pragma unroll
            for (int r = 0; r < 4; ++r) {
                const int m = m0 + wm + i * 16 + g * 4 + r;
                const int bi = m >> 10, s = m & 1023;
                const float v = (acc[i][j][r] + bb) * scale;
                const _Float16 hv = (_Float16)v;
                const int bh = bi * NH + h;
                if (mat == 0)      Qo[((size_t)bh * SEQ + s) * DV + dd] = hv;
                else if (mat == 1) Ko[((size_t)bh * SEQ + s) * DV + dd] = hv;
                else               Vto[((size_t)bh * DV + dd) * SEQ + s] = hv;
            }
        }
    }
}

// ---------------- flash attention ----------------
// grid: (S/64, B*H). block 256 = 4 waves; each wave owns 16 q-rows.
// scoresT = mfma(K_rows, Q_rows): lane (g,qc) holds scores for query qc, keys (g*4+r)+16*kf.
// PV in transposed orientation: outT[d,q] = sum_kk VT[d,kk] * PT[kk,q]; alpha/l lane-local.
__global__ __launch_bounds__(256) void attn(
    const _Float16* __restrict__ Q, const _Float16* __restrict__ K,
    const _Float16* __restrict__ Vt, float* __restrict__ out)
{
    __shared__ _Float16 P[4][16][80];   // per wave: [q][kk] with pad 80 (stride 160B)

    const int w = threadIdx.x >> 6, l = threadIdx.x & 63;
    const int qc = l & 15, g = l >> 4;
    const int qt = blockIdx.x, bh = blockIdx.y;
    const int b = bh >> 4, h = bh & 15;
    const int qrow = qt * 64 + w * 16 + qc;

    const _Float16* qptr = Q + ((size_t)bh * SEQ + qrow) * DV + g * 8;
    f16x8 qf0 = *(const f16x8*)(qptr);
    f16x8 qf1 = *(const f16x8*)(qptr + 32);

    float m_run = -1e30f, l_run = 0.f;
    f32x4 oacc[4] = {};
    const f32x4 zf = {0.f, 0.f, 0.f, 0.f};

    for (int kb = 0; kb < SEQ; kb += 64) {
        f32x4 sT[4];
#pragma unroll
        for (int kf = 0; kf < 4; ++kf) {
            const _Float16* kptr = K + ((size_t)bh * SEQ + kb + kf * 16 + qc) * DV + g * 8;
            f16x8 ka0 = *(const f16x8*)(kptr);
            f16x8 ka1 = *(const f16x8*)(kptr + 32);
            sT[kf] = __builtin_amdgcn_mfma_f32_16x16x32_f16(ka0, qf0, zf, 0, 0, 0);
            sT[kf] = __builtin_amdgcn_mfma_f32_16x16x32_f16(ka1, qf1, sT[kf], 0, 0, 0);
        }
        // online softmax (scores for query qc live in lanes qc, qc+16, qc+32, qc+48)
        float pmax = sT[0][0];
#pragma unroll
        for (int kf = 0; kf < 4; ++kf)
#pragma unroll
            for (int r = 0; r < 4; ++r) pmax = fmaxf(pmax, sT[kf][r]);
        pmax = fmaxf(pmax, __shfl_xor(pmax, 16));
        pmax = fmaxf(pmax, __shfl_xor(pmax, 32));
        const float m_new = fmaxf(m_run, pmax);
        const float alpha = __expf(m_run - m_new);
        float rsum = 0.f;
#pragma unroll
        for (int kf = 0; kf < 4; ++kf) {
            f16x4 ph;
#pragma unroll
            for (int r = 0; r < 4; ++r) {
                float p = __expf(sT[kf][r] - m_new);
                rsum += p;
                ph[r] = (_Float16)p;
            }
            *(f16x4*)&P[w][qc][kf * 16 + g * 4] = ph;   // ds_write_b64
        }
        rsum += __shfl_xor(rsum, 16);
        rsum += __shfl_xor(rsum, 32);
        l_run = l_run * alpha + rsum;
        m_run = m_new;
#pragma unroll
        for (int df = 0; df < 4; ++df) oacc[df] *= alpha;

#pragma unroll
        for (int ks = 0; ks < 2; ++ks) {
            f16x8 pb = *(const f16x8*)&P[w][qc][ks * 32 + g * 8];   // ds_read_b128
#pragma unroll
            for (int df = 0; df < 4; ++df) {
                const _Float16* vptr = Vt + ((size_t)bh * DV + df * 16 + qc) * SEQ + kb + ks * 32 + g * 8;
                f16x8 va = *(const f16x8*)(vptr);
                oacc[df] = __builtin_amdgcn_mfma_f32_16x16x32_f16(va, pb, oacc[df], 0, 0, 0);
            }
        }
    }

    const float inv = 1.0f / l_run;
    float* obase = out + ((size_t)b * SEQ + qrow) * D_MODEL + h * DV;
#pragma unroll
    for (int df = 0; df < 4; ++df) {
        float4 v4;
        v4.x = oacc[df][0] * inv; v4.y = oacc[df][1] * inv;
        v4.z = oacc[df][2] * inv; v4.w = oacc[df][3] * inv;
        *(float4*)(obase + df * 16 + g * 4) = v4;
    }
}

extern "C" void kernel_launch(void* const* d_in, const int* in_sizes, int n_in,
                              void* d_out, int out_size, void* d_ws, size_t ws_size,
                              hipStream_t stream) {
    const float* seq = (const float*)d_in[0];
    const float* Wq  = (const float*)d_in[1];
    const float* bq  = (const float*)d_in[2];
    const float* Wk  = (const float*)d_in[3];
    const float* bk  = (const float*)d_in[4];
    const float* Wv  = (const float*)d_in[5];
    const float* bv  = (const float*)d_in[6];
    float* out = (float*)d_out;

    // workspace carve (fp16 elements): seq 4M | Wq 1M | Wk 1M | Wv 1M | Q 4M | K 4M | Vt 4M = 38MB
    _Float16* seqh = (_Float16*)d_ws;
    _Float16* wqh  = seqh + (size_t)M_TOTAL * D_MODEL;
    _Float16* wkh  = wqh + (size_t)D_MODEL * D_MODEL;
    _Float16* wvh  = wkh + (size_t)D_MODEL * D_MODEL;
    _Float16* Qh   = wvh + (size_t)D_MODEL * D_MODEL;
    _Float16* Kh   = Qh + (size_t)M_TOTAL * D_MODEL;
    _Float16* Vth  = Kh + (size_t)M_TOTAL * D_MODEL;

    const int n_seq = M_TOTAL * D_MODEL;     // 4194304
    const int n_w   = D_MODEL * D_MODEL;     // 1048576
    cvt_f32_f16<<<n_seq / (256 * 8), 256, 0, stream>>>(seq, seqh, n_seq);
    cvt_f32_f16<<<n_w / (256 * 8), 256, 0, stream>>>(Wq, wqh, n_w);
    cvt_f32_f16<<<n_w / (256 * 8), 256, 0, stream>>>(Wk, wkh, n_w);
    cvt_f32_f16<<<n_w / (256 * 8), 256, 0, stream>>>(Wv, wvh, n_w);

    qkv_gemm<<<dim3(M_TOTAL / 128, 24), 256, 0, stream>>>(
        seqh, wqh, wkh, wvh, bq, bk, bv, Qh, Kh, Vth);

    attn<<<dim3(SEQ / 64, BATCH * NH), 256, 0, stream>>>(Qh, Kh, Vth, out);
}

// Round 2
// 121.488 us; speedup vs baseline: 1.5913x; 1.5913x over previous
//
#include <hip/hip_runtime.h>
#include <hip/hip_fp16.h>

typedef _Float16 f16x8 __attribute__((ext_vector_type(8)));
typedef _Float16 f16x4 __attribute__((ext_vector_type(4)));
typedef float f32x4 __attribute__((ext_vector_type(4)));

#define D_MODEL 1024
#define SEQ 1024
#define BATCH 4
#define NH 16
#define DV 64
#define M_TOTAL (BATCH * SEQ)   // 4096
#define QBLK 128

__device__ __forceinline__ void gload16(const _Float16* g, _Float16* lds) {
    __builtin_amdgcn_global_load_lds((const __attribute__((address_space(1))) void*)g,
                                     (__attribute__((address_space(3))) void*)lds,
                                     16, 0, 0);
}

// ---------------- fp32 -> fp16 convert (8 elems/thread) ----------------
__global__ void cvt_f32_f16(const float* __restrict__ s, _Float16* __restrict__ d, int n) {
    int i = (blockIdx.x * blockDim.x + threadIdx.x) * 8;
    if (i >= n) return;
    float4 a = *(const float4*)(s + i);
    float4 b = *(const float4*)(s + i + 4);
    f16x8 h;
    h[0] = (_Float16)a.x; h[1] = (_Float16)a.y; h[2] = (_Float16)a.z; h[3] = (_Float16)a.w;
    h[4] = (_Float16)b.x; h[5] = (_Float16)b.y; h[6] = (_Float16)b.z; h[7] = (_Float16)b.w;
    *(f16x8*)(d + i) = h;
}

// ---------------- fused QKV projection GEMM ----------------
// C[m,o] = sum_k X[m,k] * W[o,k] + b[o]   (NT GEMM)
// Q pre-scaled by 0.125/ln2 (log2-domain softmax downstream); V written transposed.
__global__ __launch_bounds__(256) void qkv_gemm(
    const _Float16* __restrict__ X,
    const _Float16* __restrict__ W0, const _Float16* __restrict__ W1, const _Float16* __restrict__ W2,
    const float* __restrict__ b0, const float* __restrict__ b1, const float* __restrict__ b2,
    _Float16* __restrict__ Qo, _Float16* __restrict__ Ko, _Float16* __restrict__ Vto)
{
    __shared__ _Float16 As[128][64];
    __shared__ _Float16 Bs[128][64];

    const int tid = threadIdx.x;
    const int l = tid & 63;
    const int w = tid >> 6;
    const int mt = blockIdx.x;
    const int ntg = blockIdx.y;
    const int mat = ntg >> 3;        // 0=Q 1=K 2=V
    const int nt  = ntg & 7;
    const _Float16* Wm  = (mat == 0) ? W0 : (mat == 1 ? W1 : W2);
    const float*    bia = (mat == 0) ? b0 : (mat == 1 ? b1 : b2);
    const int m0 = mt * 128, n0 = nt * 128;

    const int srow = w * 8 + (l >> 3);
    const int scol = (l & 7) * 8;
    const _Float16* xsrc = X  + (size_t)(m0 + srow) * D_MODEL + scol;
    const _Float16* wsrc = Wm + (size_t)(n0 + srow) * D_MODEL + scol;
    _Float16* aldsb = (_Float16*)As + w * 512;
    _Float16* bldsb = (_Float16*)Bs + w * 512;

    f32x4 acc[4][4] = {};
    const int wm = (w >> 1) * 64, wn = (w & 1) * 64;
    const int fr = l & 15, g = l >> 4;

    for (int kt = 0; kt < 16; ++kt) {
        const int k0 = kt * 64;
#pragma unroll
        for (int c = 0; c < 4; ++c) {
            gload16(xsrc + (size_t)(c * 32) * D_MODEL + k0, aldsb + c * 2048);
            gload16(wsrc + (size_t)(c * 32) * D_MODEL + k0, bldsb + c * 2048);
        }
        __syncthreads();
#pragma unroll
        for (int ks = 0; ks < 2; ++ks) {
            f16x8 a[4], b[4];
#pragma unroll
            for (int i = 0; i < 4; ++i) {
                a[i] = *(const f16x8*)&As[wm + i * 16 + fr][ks * 32 + g * 8];
                b[i] = *(const f16x8*)&Bs[wn + i * 16 + fr][ks * 32 + g * 8];
            }
#pragma unroll
            for (int i = 0; i < 4; ++i)
#pragma unroll
                for (int j = 0; j < 4; ++j)
                    acc[i][j] = __builtin_amdgcn_mfma_f32_16x16x32_f16(a[i], b[j], acc[i][j], 0, 0, 0);
        }
        __syncthreads();
    }

    // epilogue: bias + (Q only) 0.125/ln2 scale, scatter to per-head layouts
    const float scale = (mat == 0) ? 0.125f * 1.44269504088896340736f : 1.0f;
#pragma unroll
    for (int j = 0; j < 4; ++j) {
        const int o = n0 + wn + j * 16 + fr;
        const float bb = bia[o];
        const int h = o >> 6, dd = o & 63;
#pragma unroll
        for (int i = 0; i < 4; ++i) {
#pragma unroll
            for (int r = 0; r < 4; ++r) {
                const int m = m0 + wm + i * 16 + g * 4 + r;
                const int bi = m >> 10, s = m & 1023;
                const float v = (acc[i][j][r] + bb) * scale;
                const _Float16 hv = (_Float16)v;
                const int bh = bi * NH + h;
                if (mat == 0)      Qo[((size_t)bh * SEQ + s) * DV + dd] = hv;
                else if (mat == 1) Ko[((size_t)bh * SEQ + s) * DV + dd] = hv;
                else               Vto[((size_t)bh * DV + dd) * SEQ + s] = hv;
            }
        }
    }
}

// ---------------- flash attention v2 ----------------
// grid 512 blocks (XCD-swizzled), 4 waves/block, QBLK=128 (32 q-rows/wave).
// K,V tiles (64x64 fp16) double-buffered in LDS, staged via global_load_lds with
// XOR chunk-swizzle (chunk ^= row&7) applied on the GLOBAL source address so the
// stride-128B ds_read_b128 fragment reads are bank-conflict-free.
__global__ __launch_bounds__(256) void attn(
    const _Float16* __restrict__ Q, const _Float16* __restrict__ K,
    const _Float16* __restrict__ Vt, float* __restrict__ out)
{
    __shared__ _Float16 Kb[2][64 * 64];
    __shared__ _Float16 Vb[2][64 * 64];
    __shared__ _Float16 P[4][2][16][80];   // per wave x qg

    const int w = threadIdx.x >> 6, l = threadIdx.x & 63;
    const int qc = l & 15, g = l >> 4;

    // XCD swizzle: all 8 q-tiles of a head land on one XCD (512 % 8 == 0, bijective)
    const int fid = blockIdx.y * 8 + blockIdx.x;        // grid = (8, 64)
    const int nid = (fid & 7) * 64 + (fid >> 3);
    const int bh = nid >> 3, qt = nid & 7;
    const int b = bh >> 4, h = bh & 15;
    const int q0 = qt * QBLK + w * 32;

    // staging constants: lane covers row (w*8 + l>>3), dest chunk l&7,
    // source chunk = (l&7) ^ ((l>>3)&7)  (swizzle involution)
    const int r8 = l >> 3;
    const int cs = ((l & 7) ^ r8) * 8;                   // source col in halves
    const _Float16* Kg = K  + (size_t)bh * SEQ * DV;
    const _Float16* Vg = Vt + (size_t)bh * DV * SEQ;

    f16x8 qf[2][2];
#pragma unroll
    for (int qg = 0; qg < 2; ++qg) {
        const _Float16* qp = Q + ((size_t)bh * SEQ + q0 + qg * 16 + qc) * DV + g * 8;
        qf[qg][0] = *(const f16x8*)(qp);
        qf[qg][1] = *(const f16x8*)(qp + 32);
    }

    float m_run[2] = {-1e30f, -1e30f}, l_run[2] = {0.f, 0.f};
    f32x4 oacc[2][4] = {};

#define STAGE(buf, kb)                                                          \
    {                                                                           \
        _Float16* kd = &Kb[buf][(w * 8) * 64];                                  \
        _Float16* vd = &Vb[buf][(w * 8) * 64];                                  \
        const int row = w * 8 + r8;                                             \
        gload16(Kg + (size_t)((kb) + row) * DV + cs, kd);                       \
        gload16(Kg + (size_t)((kb) + row + 32) * DV + cs, kd + 32 * 64);        \
        gload16(Vg + (size_t)row * SEQ + (kb) + cs, vd);                        \
        gload16(Vg + (size_t)(row + 32) * SEQ + (kb) + cs, vd + 32 * 64);       \
    }

    STAGE(0, 0);
    __syncthreads();   // drains vmcnt(0): tile 0 ready

    for (int kt = 0; kt < 16; ++kt) {
        const int ct = kt & 1;
        if (kt < 15) STAGE(ct ^ 1, (kt + 1) * 64);   // prefetch next tile (flies under compute)
        const _Float16* Ktile = Kb[ct];
        const _Float16* Vtile = Vb[ct];

#pragma unroll
        for (int qg = 0; qg < 2; ++qg) {
            // ---- QK^T (swapped: scoresT), K from swizzled LDS ----
            f32x4 sT[4];
            const f32x4 zf = {0.f, 0.f, 0.f, 0.f};
#pragma unroll
            for (int kf = 0; kf < 4; ++kf) {
                const int row = kf * 16 + qc;
                f16x8 ka0 = *(const f16x8*)&Ktile[row * 64 + (((g)     ^ (qc & 7)) << 3)];
                f16x8 ka1 = *(const f16x8*)&Ktile[row * 64 + (((4 + g) ^ (qc & 7)) << 3)];
                f32x4 t = __builtin_amdgcn_mfma_f32_16x16x32_f16(ka0, qf[qg][0], zf, 0, 0, 0);
                sT[kf] = __builtin_amdgcn_mfma_f32_16x16x32_f16(ka1, qf[qg][1], t, 0, 0, 0);
            }
            // ---- online softmax (log2 domain; scores pre-scaled by 1/ln2) ----
            f32x4 mx = sT[0];
#pragma unroll
            for (int kf = 1; kf < 4; ++kf)
#pragma unroll
                for (int r = 0; r < 4; ++r) mx[r] = fmaxf(mx[r], sT[kf][r]);
            float pmax = fmaxf(fmaxf(mx[0], mx[1]), fmaxf(mx[2], mx[3]));
            pmax = fmaxf(pmax, __shfl_xor(pmax, 16));
            pmax = fmaxf(pmax, __shfl_xor(pmax, 32));
            if (!__all(pmax - m_run[qg] <= 8.0f)) {     // T13 defer-rescale (P <= 2^8)
                const float mn = fmaxf(m_run[qg], pmax);
                const float al = exp2f(m_run[qg] - mn);
                l_run[qg] *= al;
#pragma unroll
                for (int df = 0; df < 4; ++df) oacc[qg][df] *= al;
                m_run[qg] = mn;
            }
            float rsum = 0.f;
#pragma unroll
            for (int kf = 0; kf < 4; ++kf) {
                f16x4 ph;
#pragma unroll
                for (int r = 0; r < 4; ++r) {
                    const float p = exp2f(sT[kf][r] - m_run[qg]);
                    rsum += p;
                    ph[r] = (_Float16)p;
                }
                *(f16x4*)&P[w][qg][qc][kf * 16 + g * 4] = ph;
            }
            rsum += __shfl_xor(rsum, 16);
            rsum += __shfl_xor(rsum, 32);
            l_run[qg] += rsum;

            // ---- PV (transposed), V from swizzled LDS ----
#pragma unroll
            for (int ks = 0; ks < 2; ++ks) {
                f16x8 pb = *(const f16x8*)&P[w][qg][qc][ks * 32 + g * 8];
#pragma unroll
                for (int df = 0; df < 4; ++df) {
                    const int row = df * 16 + qc;
                    f16x8 va = *(const f16x8*)&Vtile[row * 64 + (((ks * 4 + g) ^ (qc & 7)) << 3)];
                    oacc[qg][df] = __builtin_amdgcn_mfma_f32_16x16x32_f16(va, pb, oacc[qg][df], 0, 0, 0);
                }
            }
        }
        __syncthreads();   // drains vmcnt(0): next tile staged + all waves done with cur
    }
#undef STAGE

#pragma unroll
    for (int qg = 0; qg < 2; ++qg) {
        const float inv = 1.0f / l_run[qg];
        float* ob = out + ((size_t)b * SEQ + q0 + qg * 16 + qc) * D_MODEL + h * DV;
#pragma unroll
        for (int df = 0; df < 4; ++df) {
            float4 v4;
            v4.x = oacc[qg][df][0] * inv; v4.y = oacc[qg][df][1] * inv;
            v4.z = oacc[qg][df][2] * inv; v4.w = oacc[qg][df][3] * inv;
            *(float4*)(ob + df * 16 + g * 4) = v4;
        }
    }
}

extern "C" void kernel_launch(void* const* d_in, const int* in_sizes, int n_in,
                              void* d_out, int out_size, void* d_ws, size_t ws_size,
                              hipStream_t stream) {
    const float* seq = (const float*)d_in[0];
    const float* Wq  = (const float*)d_in[1];
    const float* bq  = (const float*)d_in[2];
    const float* Wk  = (const float*)d_in[3];
    const float* bk  = (const float*)d_in[4];
    const float* Wv  = (const float*)d_in[5];
    const float* bv  = (const float*)d_in[6];
    float* out = (float*)d_out;

    _Float16* seqh = (_Float16*)d_ws;
    _Float16* wqh  = seqh + (size_t)M_TOTAL * D_MODEL;
    _Float16* wkh  = wqh + (size_t)D_MODEL * D_MODEL;
    _Float16* wvh  = wkh + (size_t)D_MODEL * D_MODEL;
    _Float16* Qh   = wvh + (size_t)D_MODEL * D_MODEL;
    _Float16* Kh   = Qh + (size_t)M_TOTAL * D_MODEL;
    _Float16* Vth  = Kh + (size_t)M_TOTAL * D_MODEL;

    const int n_seq = M_TOTAL * D_MODEL;
    const int n_w   = D_MODEL * D_MODEL;
    cvt_f32_f16<<<n_seq / (256 * 8), 256, 0, stream>>>(seq, seqh, n_seq);
    cvt_f32_f16<<<n_w / (256 * 8), 256, 0, stream>>>(Wq, wqh, n_w);
    cvt_f32_f16<<<n_w / (256 * 8), 256, 0, stream>>>(Wk, wkh, n_w);
    cvt_f32_f16<<<n_w / (256 * 8), 256, 0, stream>>>(Wv, wvh, n_w);

    qkv_gemm<<<dim3(M_TOTAL / 128, 24), 256, 0, stream>>>(
        seqh, wqh, wkh, wvh, bq, bk, bv, Qh, Kh, Vth);

    attn<<<dim3(SEQ / QBLK, BATCH * NH), 256, 0, stream>>>(Qh, Kh, Vth, out);
}

// Round 3
// 116.336 us; speedup vs baseline: 1.6617x; 1.0443x over previous
//
#include <hip/hip_runtime.h>
#include <hip/hip_fp16.h>

typedef _Float16 f16x8 __attribute__((ext_vector_type(8)));
typedef _Float16 f16x4 __attribute__((ext_vector_type(4)));
typedef float f32x4 __attribute__((ext_vector_type(4)));

#define D_MODEL 1024
#define SEQ 1024
#define BATCH 4
#define NH 16
#define DV 64
#define M_TOTAL (BATCH * SEQ)   // 4096
#define QBLK 128

__device__ __forceinline__ void gload16(const _Float16* g, _Float16* lds) {
    __builtin_amdgcn_global_load_lds((const __attribute__((address_space(1))) void*)g,
                                     (__attribute__((address_space(3))) void*)lds,
                                     16, 0, 0);
}

// ---------------- fp32 -> fp16 convert (8 elems/thread) ----------------
__global__ void cvt_f32_f16(const float* __restrict__ s, _Float16* __restrict__ d, int n) {
    int i = (blockIdx.x * blockDim.x + threadIdx.x) * 8;
    if (i >= n) return;
    float4 a = *(const float4*)(s + i);
    float4 b = *(const float4*)(s + i + 4);
    f16x8 h;
    h[0] = (_Float16)a.x; h[1] = (_Float16)a.y; h[2] = (_Float16)a.z; h[3] = (_Float16)a.w;
    h[4] = (_Float16)b.x; h[5] = (_Float16)b.y; h[6] = (_Float16)b.z; h[7] = (_Float16)b.w;
    *(f16x8*)(d + i) = h;
}

// three weight matrices in one launch (grid.y selects)
__global__ void cvt3_f32_f16(const float* __restrict__ s0, const float* __restrict__ s1,
                             const float* __restrict__ s2, _Float16* __restrict__ d0,
                             _Float16* __restrict__ d1, _Float16* __restrict__ d2, int n) {
    const float* s = (blockIdx.y == 0) ? s0 : (blockIdx.y == 1 ? s1 : s2);
    _Float16*    d = (blockIdx.y == 0) ? d0 : (blockIdx.y == 1 ? d1 : d2);
    int i = (blockIdx.x * blockDim.x + threadIdx.x) * 8;
    if (i >= n) return;
    float4 a = *(const float4*)(s + i);
    float4 b = *(const float4*)(s + i + 4);
    f16x8 h;
    h[0] = (_Float16)a.x; h[1] = (_Float16)a.y; h[2] = (_Float16)a.z; h[3] = (_Float16)a.w;
    h[4] = (_Float16)b.x; h[5] = (_Float16)b.y; h[6] = (_Float16)b.z; h[7] = (_Float16)b.w;
    *(f16x8*)(d + i) = h;
}

// ---------------- fused QKV projection GEMM (2-phase prefetch, T2 swizzle, T5) ----------------
// C[m,o] = sum_k X[m,k] * W[o,k] + b[o]   (NT GEMM)
// Q pre-scaled by 0.125/ln2 (log2-domain softmax downstream); V written transposed.
// LDS tiles double-buffered; XOR chunk-swizzle (stored[s] = global[s ^ (row&7)]) applied
// on the GLOBAL source address (dest stays linear for global_load_lds) so the
// stride-128B ds_read_b128 fragment reads are bank-conflict-free.
__global__ __launch_bounds__(256) void qkv_gemm(
    const _Float16* __restrict__ X,
    const _Float16* __restrict__ W0, const _Float16* __restrict__ W1, const _Float16* __restrict__ W2,
    const float* __restrict__ b0, const float* __restrict__ b1, const float* __restrict__ b2,
    _Float16* __restrict__ Qo, _Float16* __restrict__ Ko, _Float16* __restrict__ Vto)
{
    __shared__ _Float16 As[2][128 * 64];
    __shared__ _Float16 Bs[2][128 * 64];

    const int tid = threadIdx.x;
    const int l = tid & 63;
    const int w = tid >> 6;

    // T1: bijective XCD swizzle (768 % 8 == 0). Consecutive blocks on one XCD share
    // the same ntg (W-panel stays L2-resident) while streaming X panels.
    const int bid = blockIdx.x;
    const int nid = (bid & 7) * 96 + (bid >> 3);
    const int mt = nid & 31, ntg = nid >> 5;
    const int mat = ntg >> 3;        // 0=Q 1=K 2=V
    const int nt  = ntg & 7;
    const _Float16* Wm  = (mat == 0) ? W0 : (mat == 1 ? W1 : W2);
    const float*    bia = (mat == 0) ? b0 : (mat == 1 ? b1 : b2);
    const int m0 = mt * 128, n0 = nt * 128;

    // staging: wave w covers rows c*32 + w*8 + (l>>3); lane chunk l&7 (dest linear),
    // source chunk = (l&7) ^ (l>>3)  (swizzle involution within 8-row group)
    const int r8 = l >> 3;
    const int srow = w * 8 + r8;
    const int scol = ((l & 7) ^ r8) * 8;
    const _Float16* xsrc = X  + (size_t)(m0 + srow) * D_MODEL + scol;
    const _Float16* wsrc = Wm + (size_t)(n0 + srow) * D_MODEL + scol;

    f32x4 acc[4][4] = {};
    const int wm = (w >> 1) * 64, wn = (w & 1) * 64;
    const int fr = l & 15, g = l >> 4;

#define GSTAGE(buf, k0)                                                               \
    {                                                                                 \
        _Float16* ad = &As[buf][(w * 8) * 64];                                        \
        _Float16* bd = &Bs[buf][(w * 8) * 64];                                        \
        _Pragma("unroll")                                                             \
        for (int c = 0; c < 4; ++c) {                                                 \
            gload16(xsrc + (size_t)(c * 32) * D_MODEL + (k0), ad + c * 2048);         \
            gload16(wsrc + (size_t)(c * 32) * D_MODEL + (k0), bd + c * 2048);         \
        }                                                                             \
    }

    GSTAGE(0, 0);
    __syncthreads();   // drains vmcnt(0): tile 0 ready

    for (int kt = 0; kt < 16; ++kt) {
        const int cur = kt & 1;
        if (kt < 15) GSTAGE(cur ^ 1, (kt + 1) * 64);   // prefetch next tile under compute
        const _Float16* At = &As[cur][0];
        const _Float16* Bt = &Bs[cur][0];
#pragma unroll
        for (int ks = 0; ks < 2; ++ks) {
            f16x8 a[4], b[4];
#pragma unroll
            for (int i = 0; i < 4; ++i) {
                const int cg = ks * 4 + g;
                a[i] = *(const f16x8*)&At[(wm + i * 16 + fr) * 64 + ((cg ^ (fr & 7)) << 3)];
                b[i] = *(const f16x8*)&Bt[(wn + i * 16 + fr) * 64 + ((cg ^ (fr & 7)) << 3)];
            }
            __builtin_amdgcn_s_setprio(1);
#pragma unroll
            for (int i = 0; i < 4; ++i)
#pragma unroll
                for (int j = 0; j < 4; ++j)
                    acc[i][j] = __builtin_amdgcn_mfma_f32_16x16x32_f16(a[i], b[j], acc[i][j], 0, 0, 0);
            __builtin_amdgcn_s_setprio(0);
        }
        __syncthreads();   // drains vmcnt(0): next tile staged; all waves done with cur
    }
#undef GSTAGE

    // epilogue: bias + (Q only) 0.125/ln2 scale, scatter to per-head layouts
    const float scale = (mat == 0) ? 0.125f * 1.44269504088896340736f : 1.0f;
#pragma unroll
    for (int j = 0; j < 4; ++j) {
        const int o = n0 + wn + j * 16 + fr;
        const float bb = bia[o];
        const int h = o >> 6, dd = o & 63;
#pragma unroll
        for (int i = 0; i < 4; ++i) {
#pragma unroll
            for (int r = 0; r < 4; ++r) {
                const int m = m0 + wm + i * 16 + g * 4 + r;
                const int bi = m >> 10, s = m & 1023;
                const float v = (acc[i][j][r] + bb) * scale;
                const _Float16 hv = (_Float16)v;
                const int bh = bi * NH + h;
                if (mat == 0)      Qo[((size_t)bh * SEQ + s) * DV + dd] = hv;
                else if (mat == 1) Ko[((size_t)bh * SEQ + s) * DV + dd] = hv;
                else               Vto[((size_t)bh * DV + dd) * SEQ + s] = hv;
            }
        }
    }
}

// ---------------- flash attention ----------------
// grid 512 blocks (XCD-swizzled), 4 waves/block, QBLK=128 (32 q-rows/wave).
// K,V tiles (64x64 fp16) double-buffered in LDS, staged via global_load_lds with
// XOR chunk-swizzle on the GLOBAL source address.
__global__ __launch_bounds__(256) void attn(
    const _Float16* __restrict__ Q, const _Float16* __restrict__ K,
    const _Float16* __restrict__ Vt, float* __restrict__ out)
{
    __shared__ _Float16 Kb[2][64 * 64];
    __shared__ _Float16 Vb[2][64 * 64];
    __shared__ _Float16 P[4][2][16][80];   // per wave x qg

    const int w = threadIdx.x >> 6, l = threadIdx.x & 63;
    const int qc = l & 15, g = l >> 4;

    // XCD swizzle: all 8 q-tiles of a head land on one XCD (512 % 8 == 0, bijective)
    const int fid = blockIdx.y * 8 + blockIdx.x;        // grid = (8, 64)
    const int nid = (fid & 7) * 64 + (fid >> 3);
    const int bh = nid >> 3, qt = nid & 7;
    const int b = bh >> 4, h = bh & 15;
    const int q0 = qt * QBLK + w * 32;

    const int r8 = l >> 3;
    const int cs = ((l & 7) ^ r8) * 8;                   // swizzled source col (halves)
    const _Float16* Kg = K  + (size_t)bh * SEQ * DV;
    const _Float16* Vg = Vt + (size_t)bh * DV * SEQ;

    f16x8 qf[2][2];
#pragma unroll
    for (int qg = 0; qg < 2; ++qg) {
        const _Float16* qp = Q + ((size_t)bh * SEQ + q0 + qg * 16 + qc) * DV + g * 8;
        qf[qg][0] = *(const f16x8*)(qp);
        qf[qg][1] = *(const f16x8*)(qp + 32);
    }

    float m_run[2] = {-1e30f, -1e30f}, l_run[2] = {0.f, 0.f};
    f32x4 oacc[2][4] = {};

#define STAGE(buf, kb)                                                          \
    {                                                                           \
        _Float16* kd = &Kb[buf][(w * 8) * 64];                                  \
        _Float16* vd = &Vb[buf][(w * 8) * 64];                                  \
        const int row = w * 8 + r8;                                             \
        gload16(Kg + (size_t)((kb) + row) * DV + cs, kd);                       \
        gload16(Kg + (size_t)((kb) + row + 32) * DV + cs, kd + 32 * 64);        \
        gload16(Vg + (size_t)row * SEQ + (kb) + cs, vd);                        \
        gload16(Vg + (size_t)(row + 32) * SEQ + (kb) + cs, vd + 32 * 64);       \
    }

    STAGE(0, 0);
    __syncthreads();   // drains vmcnt(0): tile 0 ready

    for (int kt = 0; kt < 16; ++kt) {
        const int ct = kt & 1;
        if (kt < 15) STAGE(ct ^ 1, (kt + 1) * 64);   // prefetch next tile under compute
        const _Float16* Ktile = Kb[ct];
        const _Float16* Vtile = Vb[ct];

#pragma unroll
        for (int qg = 0; qg < 2; ++qg) {
            // ---- QK^T (swapped: scoresT), K from swizzled LDS ----
            f32x4 sT[4];
            const f32x4 zf = {0.f, 0.f, 0.f, 0.f};
            __builtin_amdgcn_s_setprio(1);
#pragma unroll
            for (int kf = 0; kf < 4; ++kf) {
                const int row = kf * 16 + qc;
                f16x8 ka0 = *(const f16x8*)&Ktile[row * 64 + (((g)     ^ (qc & 7)) << 3)];
                f16x8 ka1 = *(const f16x8*)&Ktile[row * 64 + (((4 + g) ^ (qc & 7)) << 3)];
                f32x4 t = __builtin_amdgcn_mfma_f32_16x16x32_f16(ka0, qf[qg][0], zf, 0, 0, 0);
                sT[kf] = __builtin_amdgcn_mfma_f32_16x16x32_f16(ka1, qf[qg][1], t, 0, 0, 0);
            }
            __builtin_amdgcn_s_setprio(0);
            // ---- online softmax (log2 domain; scores pre-scaled by 1/ln2) ----
            f32x4 mx = sT[0];
#pragma unroll
            for (int kf = 1; kf < 4; ++kf)
#pragma unroll
                for (int r = 0; r < 4; ++r) mx[r] = fmaxf(mx[r], sT[kf][r]);
            float pmax = fmaxf(fmaxf(mx[0], mx[1]), fmaxf(mx[2], mx[3]));
            pmax = fmaxf(pmax, __shfl_xor(pmax, 16));
            pmax = fmaxf(pmax, __shfl_xor(pmax, 32));
            if (!__all(pmax - m_run[qg] <= 8.0f)) {     // T13 defer-rescale (P <= 2^8)
                const float mn = fmaxf(m_run[qg], pmax);
                const float al = exp2f(m_run[qg] - mn);
                l_run[qg] *= al;
#pragma unroll
                for (int df = 0; df < 4; ++df) oacc[qg][df] *= al;
                m_run[qg] = mn;
            }
            float rsum = 0.f;
#pragma unroll
            for (int kf = 0; kf < 4; ++kf) {
                f16x4 ph;
#pragma unroll
                for (int r = 0; r < 4; ++r) {
                    const float p = exp2f(sT[kf][r] - m_run[qg]);
                    rsum += p;
                    ph[r] = (_Float16)p;
                }
                *(f16x4*)&P[w][qg][qc][kf * 16 + g * 4] = ph;
            }
            rsum += __shfl_xor(rsum, 16);
            rsum += __shfl_xor(rsum, 32);
            l_run[qg] += rsum;

            // ---- PV (transposed), V from swizzled LDS ----
            __builtin_amdgcn_s_setprio(1);
#pragma unroll
            for (int ks = 0; ks < 2; ++ks) {
                f16x8 pb = *(const f16x8*)&P[w][qg][qc][ks * 32 + g * 8];
#pragma unroll
                for (int df = 0; df < 4; ++df) {
                    const int row = df * 16 + qc;
                    f16x8 va = *(const f16x8*)&Vtile[row * 64 + (((ks * 4 + g) ^ (qc & 7)) << 3)];
                    oacc[qg][df] = __builtin_amdgcn_mfma_f32_16x16x32_f16(va, pb, oacc[qg][df], 0, 0, 0);
                }
            }
            __builtin_amdgcn_s_setprio(0);
        }
        __syncthreads();   // drains vmcnt(0): next tile staged + all waves done with cur
    }
#undef STAGE

#pragma unroll
    for (int qg = 0; qg < 2; ++qg) {
        const float inv = 1.0f / l_run[qg];
        float* ob = out + ((size_t)b * SEQ + q0 + qg * 16 + qc) * D_MODEL + h * DV;
#pragma unroll
        for (int df = 0; df < 4; ++df) {
            float4 v4;
            v4.x = oacc[qg][df][0] * inv; v4.y = oacc[qg][df][1] * inv;
            v4.z = oacc[qg][df][2] * inv; v4.w = oacc[qg][df][3] * inv;
            *(float4*)(ob + df * 16 + g * 4) = v4;
        }
    }
}

extern "C" void kernel_launch(void* const* d_in, const int* in_sizes, int n_in,
                              void* d_out, int out_size, void* d_ws, size_t ws_size,
                              hipStream_t stream) {
    const float* seq = (const float*)d_in[0];
    const float* Wq  = (const float*)d_in[1];
    const float* bq  = (const float*)d_in[2];
    const float* Wk  = (const float*)d_in[3];
    const float* bk  = (const float*)d_in[4];
    const float* Wv  = (const float*)d_in[5];
    const float* bv  = (const float*)d_in[6];
    float* out = (float*)d_out;

    _Float16* seqh = (_Float16*)d_ws;
    _Float16* wqh  = seqh + (size_t)M_TOTAL * D_MODEL;
    _Float16* wkh  = wqh + (size_t)D_MODEL * D_MODEL;
    _Float16* wvh  = wkh + (size_t)D_MODEL * D_MODEL;
    _Float16* Qh   = wvh + (size_t)D_MODEL * D_MODEL;
    _Float16* Kh   = Qh + (size_t)M_TOTAL * D_MODEL;
    _Float16* Vth  = Kh + (size_t)M_TOTAL * D_MODEL;

    const int n_seq = M_TOTAL * D_MODEL;
    const int n_w   = D_MODEL * D_MODEL;
    cvt_f32_f16<<<n_seq / (256 * 8), 256, 0, stream>>>(seq, seqh, n_seq);
    cvt3_f32_f16<<<dim3(n_w / (256 * 8), 3), 256, 0, stream>>>(Wq, Wk, Wv, wqh, wkh, wvh, n_w);

    qkv_gemm<<<768, 256, 0, stream>>>(
        seqh, wqh, wkh, wvh, bq, bk, bv, Qh, Kh, Vth);

    attn<<<dim3(SEQ / QBLK, BATCH * NH), 256, 0, stream>>>(Qh, Kh, Vth, out);
}